// Round 15
// baseline (540.560 us; speedup 1.0000x reference)
//
#include <hip/hip_runtime.h>
#include <math.h>

typedef float2 c2;

#define S_IDX(i) ((i) ^ (((i) >> 5) & 15))
#define HSTR 530                       // half-slab line stride in c2 (16 rows x 33 + 2 pad)

__device__ __forceinline__ c2 cmul(c2 a, c2 b){
  return make_float2(a.x*b.x - a.y*b.y, a.x*b.y + a.y*b.x);
}

__constant__ float2 c_tw32[16] = {
  {1.0f, 0.0f},
  {0.980785280f, 0.195090322f},
  {0.923879533f, 0.382683432f},
  {0.831469612f, 0.555570233f},
  {0.707106781f, 0.707106781f},
  {0.555570233f, 0.831469612f},
  {0.382683432f, 0.923879533f},
  {0.195090322f, 0.980785280f},
  {0.0f, 1.0f},
  {-0.195090322f, 0.980785280f},
  {-0.382683432f, 0.923879533f},
  {-0.555570233f, 0.831469612f},
  {-0.707106781f, 0.707106781f},
  {-0.831469612f, 0.555570233f},
  {-0.923879533f, 0.382683432f},
  {-0.980785280f, 0.195090322f}
};

__constant__ float c_lnfo[5]  = {1.0986123f, 1.8405496f, 2.5824700f, 3.3244106f, 4.0663219f};
__constant__ float c_angl[6]  = {0.0f, 0.5235988f, 1.0471976f, 1.5707963f, 2.0943951f, 2.6179939f};
__constant__ float c_cosA[6] = {1.0f, 0.8660254038f, 0.5f, 6.123233996e-17f, -0.5f, -0.8660254038f};
__constant__ float c_sinA[6] = {0.0f, 0.5f, 0.8660254038f, 1.0f, 0.8660254038f, 0.5f};

// ---------------- Stockham row-FFT machinery (twiddle-precomputed) ----------------

template<int SIGN>
__device__ __forceinline__ void make_tw3(int t, c2* w1, c2* w2, c2* w3){
#pragma unroll
  for (int k = 0; k < 5; ++k){
    const int s = 1 << (2*k);
    const float ang = (float)SIGN * 0.00613592315154256f * (float)(t & ~(s-1));
    sincosf(ang, &w1[k].y, &w1[k].x);
    w2[k] = cmul(w1[k], w1[k]);
    w3[k] = cmul(w2[k], w1[k]);
  }
}

template<int SIGN>
__device__ __forceinline__ void fft1024(c2* bufA, c2* bufB, int t,
                                        const c2* w1a, const c2* w2a, const c2* w3a){
  c2* cur = bufA; c2* oth = bufB;
#pragma unroll
  for (int k = 0; k < 5; ++k){
    const int s = 1 << (2*k);
    const int q = t & (s - 1);
    c2 a = cur[S_IDX(t)];
    c2 b = cur[S_IDX(t + 256)];
    c2 c = cur[S_IDX(t + 512)];
    c2 d = cur[S_IDX(t + 768)];
    c2 apc = make_float2(a.x + c.x, a.y + c.y);
    c2 amc = make_float2(a.x - c.x, a.y - c.y);
    c2 bpd = make_float2(b.x + d.x, b.y + d.y);
    c2 bmd = make_float2(b.x - d.x, b.y - d.y);
    c2 y0 = make_float2(apc.x + bpd.x, apc.y + bpd.y);
    c2 e2 = make_float2(apc.x - bpd.x, apc.y - bpd.y);
    const float S4 = (float)SIGN;
    c2 u1 = make_float2(amc.x - S4*bmd.y, amc.y + S4*bmd.x);
    c2 u3 = make_float2(amc.x + S4*bmd.y, amc.y - S4*bmd.x);
    c2 y1 = cmul(u1, w1a[k]);
    c2 y2 = cmul(e2, w2a[k]);
    c2 y3 = cmul(u3, w3a[k]);
    const int bw = 4*t - 3*q;
    oth[S_IDX(bw)]       = y0;
    oth[S_IDX(bw + s)]   = y1;
    oth[S_IDX(bw + 2*s)] = y2;
    oth[S_IDX(bw + 3*s)] = y3;
    c2* tmp = cur; cur = oth; oth = tmp;
    __syncthreads();
  }
}

// ---------------- register FFT-32 + four-step column FFT (split-exchange) ----------------

__device__ __forceinline__ constexpr int rev5(int k){
  return ((k&1)<<4) | ((k&2)<<2) | (k&4) | ((k&8)>>2) | ((k>>4)&1);
}

template<int SIGN, int M>
__device__ __forceinline__ void stage32(c2* r){
#pragma unroll
  for (int g = 0; g < 32; g += 2*M){
#pragma unroll
    for (int i = 0; i < M; ++i){
      const c2 a = r[g+i], b = r[g+i+M];
      r[g+i] = make_float2(a.x+b.x, a.y+b.y);
      c2 d = make_float2(a.x-b.x, a.y-b.y);
      if (i != 0){
        const float2 tt = c_tw32[i*(16/M)];
        d = cmul(d, make_float2(tt.x, (float)SIGN*tt.y));
      }
      r[g+i+M] = d;
    }
  }
}

template<int SIGN>
__device__ __forceinline__ void fft32(c2* r){
  stage32<SIGN,16>(r);
  stage32<SIGN,8>(r);
  stage32<SIGN,4>(r);
  stage32<SIGN,2>(r);
  stage32<SIGN,1>(r);
}

// Split H-exchange: rows 0..15 in phase A, rows 16..31 reuse the same half-slab.
// LDS per line = HSTR c2 (~4.2 KB); 3 syncs. Twiddle values identical to the
// monolithic version (wc refreshed via sincosf at every d%8==0).
template<int SIGN>
__device__ __forceinline__ void fourstep_mid_split(c2* r, c2* line, int idx){
  const float ang = (float)SIGN * 0.006135923151542565f * (float)idx;
  c2 wst; sincosf(ang, &wst.y, &wst.x);
  c2 wc = make_float2(1.f, 0.f);
  // phase A: d = 0..15 -> half-rows 0..15
#pragma unroll
  for (int d = 0; d < 16; ++d){
    if ((d & 7) == 0 && d != 0){ float s, c; sincosf(ang*(float)d, &s, &c); wc = make_float2(c, s); }
    c2 v = r[rev5(d)];
    if (d != 0) v = cmul(v, wc);
    line[33*d + idx] = v;
    wc = cmul(wc, wst);
  }
  __syncthreads();
  c2 tmp[32];
  const bool lo = idx < 16;
  if (lo){
#pragma unroll
    for (int b = 0; b < 32; ++b) tmp[b] = line[33*idx + b];
  }
  __syncthreads();
  // phase B: d = 16..31 -> half-rows 0..15 (reused)
#pragma unroll
  for (int d = 16; d < 32; ++d){
    if ((d & 7) == 0){ float s, c; sincosf(ang*(float)d, &s, &c); wc = make_float2(c, s); }
    c2 v = cmul(r[rev5(d)], wc);
    line[33*(d-16) + idx] = v;
    wc = cmul(wc, wst);
  }
  __syncthreads();
  if (!lo){
#pragma unroll
    for (int b = 0; b < 32; ++b) tmp[b] = line[33*(idx-16) + b];
  }
#pragma unroll
  for (int b = 0; b < 32; ++b) r[b] = tmp[b];
  fft32<SIGN>(r);
}

// Column FFT: block owns 8 columns of one plane, in-place, direct global I/O.
template<int SIGN>
__global__ __launch_bounds__(256, 4) void k_col_fft(c2* __restrict__ Z){
  __shared__ c2 slab[8*HSTR];
  const int t = threadIdx.x;
  c2* base = Z + (size_t)blockIdx.y * 1048576;
  const int sub = t & 7, idx = t >> 3;
  const int col = blockIdx.x*8 + sub;
  c2 r[32];
#pragma unroll
  for (int a = 0; a < 32; ++a)
    r[a] = base[(size_t)(32*a + idx)*1024 + col];
  fft32<SIGN>(r);
  fourstep_mid_split<SIGN>(r, slab + sub*HSTR, idx);
#pragma unroll
  for (int c = 0; c < 32; ++c)
    base[(size_t)(32*c + idx)*1024 + col] = r[rev5(c)];
}

// ---------------- filter tables, [ky (row)][kx (col)] layout ----------------

__global__ __launch_bounds__(256) void k_filt_tab(float* __restrict__ lnrT, float* __restrict__ thetaT){
  const int r = blockIdx.x;           // ky
  const int t = threadIdx.x;
  const float yy = (float)(r < 512 ? r : r - 1024) * (1.0f/1024.0f);
#pragma unroll
  for (int j = 0; j < 4; ++j){
    const int c = t + 256*j;          // kx
    const float xx = (float)(c < 512 ? c : c - 1024) * (1.0f/1024.0f);
    const float radius = sqrtf(xx*xx + yy*yy);
    float lnr = logf(radius);
    if (r == 0 && c == 0) lnr = __int_as_float(0x7F800000);  // +inf -> filter 0 at DC
    lnrT[r*1024 + c] = lnr;
    thetaT[r*1024 + c] = atan2f(-yy, xx);
  }
}

// Row FFT of the real image: out[y][kx].
__global__ __launch_bounds__(256) void k_fft_fwd_real(const float* __restrict__ in, c2* __restrict__ out){
  const int t = threadIdx.x;
  __shared__ c2 bufA[1024];
  __shared__ c2 bufB[1024];
  c2 w1[5], w2[5], w3[5]; make_tw3<-1>(t, w1, w2, w3);
  for (int rr = 0; rr < 4; ++rr){
    const int row = blockIdx.x * 4 + rr;
    const float* src = in + (size_t)row * 1024;
    c2* dst = out + (size_t)row * 1024;
#pragma unroll
    for (int j = 0; j < 4; ++j){
      const int q = t + 256*j;
      bufA[S_IDX(q)] = make_float2(src[q], 0.0f);
    }
    __syncthreads();
    fft1024<-1>(bufA, bufB, t, w1, w2, w3);
#pragma unroll
    for (int j = 0; j < 4; ++j){ const int q = t + 256*j; dst[q] = bufB[S_IDX(q)]; }
    __syncthreads();
  }
}

// Orientation-grouped filter + row-IFFT over kx.  Row = ky of F[ky][kx].
__global__ __launch_bounds__(256) void k_fft_inv_filter_g(const c2* __restrict__ F, c2* __restrict__ Z,
                                                          const float* __restrict__ lnrT,
                                                          const float* __restrict__ thetaT, int orient0){
  const int t = threadIdx.x;
  const int orient = orient0 + blockIdx.y;
  const float angl = c_angl[orient];
  __shared__ c2 bufA[1024];
  __shared__ c2 bufB[1024];
  __shared__ c2 Frow[1024];
  __shared__ float commSh[1024];
  __shared__ float lnrSh[1024];
  c2 w1[5], w2[5], w3[5]; make_tw3<1>(t, w1, w2, w3);
  for (int rr = 0; rr < 4; ++rr){
    const int row = blockIdx.x * 4 + rr;      // ky
    const c2* src = F + (size_t)row * 1024;
    const float* lnrR = lnrT + (size_t)row * 1024;
    const float* thR  = thetaT + (size_t)row * 1024;
#pragma unroll
    for (int j = 0; j < 4; ++j){
      const int q = t + 256*j;
      Frow[q] = src[q];
      const float lnr = lnrR[q];
      const float th  = thR[q];
      const float lp = 1.0f/(1.0f + __expf(fmaf(30.f, lnr, 23.955231f)));
      float d = th - angl;
      if (d <= -3.14159274f) d += 6.28318548f;
      const float dth = fminf(fabsf(d)*3.0f, 3.14159274f);
      const float spr = 0.5f*(__cosf(dth)+1.0f);
      lnrSh[q] = lnr;
      commSh[q] = lp*spr;
    }
    __syncthreads();
    for (int s = 0; s < 5; ++s){
      const float lnfo = c_lnfo[s];
      c2* dst = Z + ((size_t)blockIdx.y*5 + s) * 1048576 + (size_t)row * 1024;
#pragma unroll
      for (int j = 0; j < 4; ++j){
        const int q = t + 256*j;
        const float u = lnrSh[q] + lnfo;
        const float f = __expf(-u*u*1.3989572f) * commSh[q];
        const c2 v = Frow[q];
        bufA[S_IDX(q)] = make_float2(v.x*f, v.y*f);
      }
      __syncthreads();
      fft1024<1>(bufA, bufB, t, w1, w2, w3);
#pragma unroll
      for (int j = 0; j < 4; ++j){ const int q = t + 256*j; dst[q] = bufB[S_IDX(q)]; }
      __syncthreads();
    }
  }
}

// ---------------- exact median via 3-level radix select (12/12/8 bits) ----------

__device__ __forceinline__ unsigned amp_bits(const c2 v){
  return __float_as_uint(sqrtf(v.x*v.x + v.y*v.y));
}

__global__ __launch_bounds__(256) void k_med_p1b(const c2* __restrict__ Zb, size_t oStride,
                                                 unsigned* __restrict__ g1, int oBase){
  __shared__ unsigned h[4][4096];
  const int t = threadIdx.x;
  const int wv = t >> 6;
  const c2* z0 = Zb + (size_t)blockIdx.y * oStride;
  unsigned* gg = g1 + (size_t)(oBase + blockIdx.y) * 4096;
  for (int j = t; j < 4*4096; j += 256) ((unsigned*)h)[j] = 0;
  __syncthreads();
  const int base = blockIdx.x * 16384;
  for (int it = 0; it < 64; ++it){
    const unsigned bits = amp_bits(z0[base + it*256 + t]);
    atomicAdd(&h[wv][bits >> 20], 1u);
  }
  __syncthreads();
  for (int j = t; j < 4096; j += 256){
    const unsigned s = h[0][j] + h[1][j] + h[2][j] + h[3][j];
    if (s) atomicAdd(&gg[j], s);
  }
}

__global__ __launch_bounds__(256) void k_sel1b(const unsigned* __restrict__ g1,
                                               unsigned* __restrict__ sc1,
                                               unsigned* __restrict__ g2, int oBase){
  __shared__ unsigned partial[256];
  const int t = threadIdx.x;
  const int oo = oBase + blockIdx.x;
  const unsigned* gg = g1 + (size_t)oo * 4096;
  unsigned loc[16]; unsigned s = 0;
#pragma unroll
  for (int j = 0; j < 16; ++j){ loc[j] = gg[t*16 + j]; s += loc[j]; }
  partial[t] = s;
  __syncthreads();
  unsigned p = 0;
  for (int u = 0; u < t; ++u) p += partial[u];
  for (int which = 0; which < 2; ++which){
    const unsigned R = 524287u + (unsigned)which;
    if (R >= p && R - p < s){
      unsigned cum = p;
      for (int j = 0; j < 16; ++j){
        if (R - cum < loc[j]){ sc1[oo*4 + which*2] = (unsigned)(t*16 + j); sc1[oo*4 + which*2+1] = R - cum; break; }
        cum += loc[j];
      }
    }
  }
  for (int j = t; j < 8192; j += 256) g2[(size_t)oo*8192 + j] = 0;
}

__global__ __launch_bounds__(256) void k_med_p2b(const c2* __restrict__ Zb, size_t oStride,
                                                 const unsigned* __restrict__ sc1,
                                                 unsigned* __restrict__ g2, int oBase){
  __shared__ unsigned h[2][4096];
  const int t = threadIdx.x;
  const int oo = oBase + blockIdx.y;
  const c2* z0 = Zb + (size_t)blockIdx.y * oStride;
  unsigned* gg = g2 + (size_t)oo * 8192;
  for (int j = t; j < 8192; j += 256) ((unsigned*)h)[j] = 0;
  __syncthreads();
  const unsigned b0 = sc1[oo*4 + 0], b1 = sc1[oo*4 + 2];
  const int base = blockIdx.x * 16384;
  for (int it = 0; it < 64; ++it){
    const unsigned bits = amp_bits(z0[base + it*256 + t]);
    const unsigned top = bits >> 20;
    const unsigned mid = (bits >> 8) & 4095u;
    if (top == b0)      atomicAdd(&h[0][mid], 1u);
    else if (top == b1) atomicAdd(&h[1][mid], 1u);
  }
  __syncthreads();
  for (int j = t; j < 4096; j += 256){
    if (h[0][j]) atomicAdd(&gg[j], h[0][j]);
    if (h[1][j]) atomicAdd(&gg[4096 + j], h[1][j]);
  }
}

__global__ __launch_bounds__(256) void k_sel2b(const unsigned* __restrict__ g2,
                                               const unsigned* __restrict__ sc1,
                                               unsigned* __restrict__ sc2,
                                               unsigned* __restrict__ g3, int oBase){
  __shared__ unsigned partial[256];
  const int t = threadIdx.x;
  const int oo = oBase + blockIdx.x;
  const unsigned b0 = sc1[oo*4+0], lr0 = sc1[oo*4+1], b1 = sc1[oo*4+2], lr1 = sc1[oo*4+3];
  for (int which = 0; which < 2; ++which){
    const unsigned* hh = g2 + (size_t)oo*8192 + ((which == 1 && b1 != b0) ? 4096 : 0);
    const unsigned R = which ? lr1 : lr0;
    unsigned loc[16]; unsigned s = 0;
#pragma unroll
    for (int j = 0; j < 16; ++j){ loc[j] = hh[t*16 + j]; s += loc[j]; }
    partial[t] = s;
    __syncthreads();
    unsigned p = 0;
    for (int u = 0; u < t; ++u) p += partial[u];
    if (R >= p && R - p < s){
      unsigned cum = p;
      for (int j = 0; j < 16; ++j){
        if (R - cum < loc[j]){ sc2[oo*4 + which*2] = (unsigned)(t*16 + j); sc2[oo*4 + which*2+1] = R - cum; break; }
        cum += loc[j];
      }
    }
    __syncthreads();
  }
  for (int j = t; j < 512; j += 256) g3[(size_t)oo*512 + j] = 0;
}

__global__ __launch_bounds__(256) void k_med_p3b(const c2* __restrict__ Zb, size_t oStride,
                                                 const unsigned* __restrict__ sc1,
                                                 const unsigned* __restrict__ sc2,
                                                 unsigned* __restrict__ g3, int oBase){
  __shared__ unsigned h[2][256];
  const int t = threadIdx.x;
  const int oo = oBase + blockIdx.y;
  const c2* z0 = Zb + (size_t)blockIdx.y * oStride;
  unsigned* gg = g3 + (size_t)oo * 512;
  h[0][t] = 0; h[1][t] = 0;
  __syncthreads();
  const unsigned k0 = (sc1[oo*4+0] << 12) | sc2[oo*4+0];
  const unsigned k1 = (sc1[oo*4+2] << 12) | sc2[oo*4+2];
  const int base = blockIdx.x * 16384;
  for (int it = 0; it < 64; ++it){
    const unsigned bits = amp_bits(z0[base + it*256 + t]);
    const unsigned key = bits >> 8;
    if (key == k0)       atomicAdd(&h[0][bits & 255u], 1u);
    else if (key == k1)  atomicAdd(&h[1][bits & 255u], 1u);
  }
  __syncthreads();
  if (h[0][t]) atomicAdd(&gg[t], h[0][t]);
  if (h[1][t]) atomicAdd(&gg[256 + t], h[1][t]);
}

__global__ __launch_bounds__(256) void k_sel3b(const unsigned* __restrict__ g3,
                                               const unsigned* __restrict__ sc1,
                                               const unsigned* __restrict__ sc2,
                                               float* __restrict__ Tval, int oBase){
  __shared__ unsigned partial[256];
  __shared__ float vres[2];
  const int t = threadIdx.x;
  const int oo = oBase + blockIdx.x;
  const unsigned k0 = (sc1[oo*4+0] << 12) | sc2[oo*4+0];
  const unsigned k1 = (sc1[oo*4+2] << 12) | sc2[oo*4+2];
  for (int which = 0; which < 2; ++which){
    const unsigned* hh = g3 + (size_t)oo*512 + ((which == 1 && k1 != k0) ? 256 : 0);
    const unsigned R = which ? sc2[oo*4+3] : sc2[oo*4+1];
    partial[t] = hh[t];
    __syncthreads();
    unsigned p = 0;
    for (int u = 0; u < t; ++u) p += partial[u];
    if (R >= p && R - p < partial[t]){
      const unsigned key = which ? k1 : k0;
      vres[which] = __uint_as_float((key << 8) | (unsigned)t);
    }
    __syncthreads();
  }
  if (t == 0){
    const float med = 0.5f * (vres[0] + vres[1]);
    const float tau = med / 1.17741001f;              // sqrt(ln 4)
    const float totalTau = tau * 1.8623464f;          // (1-(1/2.1)^5)/(1-1/2.1)
    const float T = totalTau * 1.25331414f + 2.0f * totalTau * 0.65513638f;
    Tval[oo] = T;
  }
}

// ---------------- fused per-pixel: all 6 orientations + final M,m ----------------

__global__ __launch_bounds__(256) void k_pix_all(const c2* __restrict__ Z, const float* __restrict__ Tval,
                                                 float* __restrict__ out){
  const int i = blockIdx.x * 256 + threadIdx.x;
  float covx2 = 0.f, covy2 = 0.f, covxy = 0.f;
#pragma unroll
  for (int o = 0; o < 6; ++o){
    const float T = Tval[o];
    float E[5], O[5];
    float sumE = 0.f, sumO = 0.f, sumAn = 0.f, maxAn = 0.f;
#pragma unroll
    for (int s = 0; s < 5; ++s){
      const c2 z = Z[(size_t)(o*5 + s) * 1048576 + i];
      O[s] = z.x; E[s] = z.y;
      const float an = sqrtf(z.x*z.x + z.y*z.y);
      sumE += E[s]; sumO += O[s]; sumAn += an; maxAn = fmaxf(maxAn, an);
    }
    const float XE = sqrtf(sumE*sumE + sumO*sumO) + 1e-4f;
    const float ME = sumE / XE, MO = sumO / XE;
    float energy = 0.f;
#pragma unroll
    for (int s = 0; s < 5; ++s)
      energy += E[s]*ME + O[s]*MO - fabsf(E[s]*MO - O[s]*ME);
    energy = fmaxf(energy - T, 0.f);
    const float width = (sumAn / (maxAn + 1e-4f) - 1.0f) * 0.25f;
    const float weight = 1.0f / (1.0f + expf((0.5f - width) * 10.0f));
    const float PC = weight * energy / sumAn;
    const float cx = PC * c_cosA[o], cy = PC * c_sinA[o];
    covx2 += cx*cx; covy2 += cy*cy; covxy += cx*cy;
  }
  covx2 *= (1.0f/3.0f);
  covy2 *= (1.0f/3.0f);
  covxy *= (4.0f/6.0f);
  const float dnm = sqrtf(covxy*covxy + (covx2 - covy2)*(covx2 - covy2)) + 1e-4f;
  const float ss = covy2 + covx2;
  out[i] = (ss + dnm) / 2.0f;
  out[1048576 + i] = (ss - dnm) / 2.0f;
}

// ---------------- fallback per-orientation pixel kernels ----------------

__global__ __launch_bounds__(256) void k_pix(const c2* __restrict__ Z, const float* __restrict__ Tp,
                                             float cA, float sA,
                                             float* __restrict__ ax2, float* __restrict__ ay2,
                                             float* __restrict__ axy, int first){
  const int i = blockIdx.x * 256 + threadIdx.x;
  const float T = *Tp;
  float E[5], O[5];
  float sumE = 0.f, sumO = 0.f, sumAn = 0.f, maxAn = 0.f;
#pragma unroll
  for (int s = 0; s < 5; ++s){
    const c2 z = Z[(size_t)s * 1048576 + i];
    O[s] = z.x; E[s] = z.y;
    const float an = sqrtf(z.x*z.x + z.y*z.y);
    sumE += E[s]; sumO += O[s]; sumAn += an; maxAn = fmaxf(maxAn, an);
  }
  const float XE = sqrtf(sumE*sumE + sumO*sumO) + 1e-4f;
  const float ME = sumE / XE, MO = sumO / XE;
  float energy = 0.f;
#pragma unroll
  for (int s = 0; s < 5; ++s)
    energy += E[s]*ME + O[s]*MO - fabsf(E[s]*MO - O[s]*ME);
  energy = fmaxf(energy - T, 0.f);
  const float width = (sumAn / (maxAn + 1e-4f) - 1.0f) * 0.25f;
  const float weight = 1.0f / (1.0f + expf((0.5f - width) * 10.0f));
  const float PC = weight * energy / sumAn;
  const float cx = PC * cA, cy = PC * sA;
  if (first){ ax2[i] = cx*cx; ay2[i] = cy*cy; axy[i] = cx*cy; }
  else      { ax2[i] += cx*cx; ay2[i] += cy*cy; axy[i] += cx*cy; }
}

__global__ __launch_bounds__(256) void k_final(const float* __restrict__ ax2, const float* __restrict__ ay2,
                                               const float* __restrict__ axy, float* __restrict__ out){
  const int i = blockIdx.x * 256 + threadIdx.x;
  const float cx2 = ax2[i] / 3.0f;
  const float cy2 = ay2[i] / 3.0f;
  const float cxy = 4.0f * axy[i] / 6.0f;
  const float dnm = sqrtf(cxy*cxy + (cx2 - cy2)*(cx2 - cy2)) + 1e-4f;
  const float ss = cy2 + cx2;
  out[i] = (ss + dnm) / 2.0f;
  out[1048576 + i] = (ss - dnm) / 2.0f;
}

extern "C" void kernel_launch(void* const* d_in, const int* in_sizes, int n_in,
                              void* d_out, int out_size, void* d_ws, size_t ws_size,
                              hipStream_t stream){
  (void)in_sizes; (void)n_in; (void)out_size;
  const float* img = (const float*)d_in[0];
  float* out = (float*)d_out;
  char* w = (char*)d_ws;

  const dim3 th(256);

  if (ws_size >= (size_t)268435456){
    // -------- full-batch path, 256 MiB --------
    c2* F  = (c2*)(w);
    c2* Z  = (c2*)(w + 8388608);
    float* lnrT   = (float*)(w + 260046848);
    float* thetaT = (float*)(w + 264241152);
    unsigned* g1  = (unsigned*)(w);             // aliases F; F's last read is filter_g
    unsigned* g2  = (unsigned*)(w + 98304);
    unsigned* g3  = (unsigned*)(w + 294912);
    unsigned* sc1 = (unsigned*)(w + 307200);
    unsigned* sc2 = (unsigned*)(w + 307328);
    float* Tval   = (float*)(w + 307456);

    k_filt_tab<<<dim3(1024), th, 0, stream>>>(lnrT, thetaT);

    // forward 2D FFT: rowFFT -> F[y][kx]; colFFT over y -> F[ky][kx]
    k_fft_fwd_real<<<dim3(256), th, 0, stream>>>(img, F);
    k_col_fft<-1><<<dim3(128, 1), th, 0, stream>>>(F);

    // 30 channels: filter + row IFFT over kx -> Z[ky][x]; col IFFT over ky -> z[y][x]
    k_fft_inv_filter_g<<<dim3(256, 6), th, 0, stream>>>(F, Z, lnrT, thetaT, 0);
    hipMemsetAsync(g1, 0, 6*16384, stream);     // F no longer needed
    k_col_fft<1><<<dim3(128, 30), th, 0, stream>>>(Z);

    // medians for 6 orientations (scale-0 planes)
    const size_t oStride = (size_t)5 * 1048576;
    k_med_p1b<<<dim3(64, 6), th, 0, stream>>>(Z, oStride, g1, 0);
    k_sel1b<<<dim3(6), th, 0, stream>>>(g1, sc1, g2, 0);
    k_med_p2b<<<dim3(64, 6), th, 0, stream>>>(Z, oStride, sc1, g2, 0);
    k_sel2b<<<dim3(6), th, 0, stream>>>(g2, sc1, sc2, g3, 0);
    k_med_p3b<<<dim3(64, 6), th, 0, stream>>>(Z, oStride, sc1, sc2, g3, 0);
    k_sel3b<<<dim3(6), th, 0, stream>>>(g3, sc1, sc2, Tval, 0);

    // fused per-pixel PC + covariance + M,m
    k_pix_all<<<dim3(4096), th, 0, stream>>>(Z, Tval, out);
  } else {
    // -------- fallback: per-orientation (~72 MB) --------
    c2* F   = (c2*)(w);
    c2* C5  = (c2*)(w + 8388608);                 // 5 planes, 40 MB
    float* lnrT   = (float*)(w + 50331648);
    float* thetaT = (float*)(w + 54525952);
    float* ax2 = (float*)(w + 58720256);
    float* ay2 = ax2 + 1048576;
    float* axy = ay2 + 1048576;
    unsigned* g1  = (unsigned*)(w + 71303168);
    unsigned* g2  = (unsigned*)(w + 71319552);
    unsigned* g3  = (unsigned*)(w + 71352320);
    unsigned* sc1 = (unsigned*)(w + 71354368);
    unsigned* sc2 = (unsigned*)(w + 71354496);
    float* Tval   = (float*)(w + 71354624);

    k_filt_tab<<<dim3(1024), th, 0, stream>>>(lnrT, thetaT);
    k_fft_fwd_real<<<dim3(256), th, 0, stream>>>(img, F);
    k_col_fft<-1><<<dim3(128, 1), th, 0, stream>>>(F);

    for (int o = 0; o < 6; ++o){
      k_fft_inv_filter_g<<<dim3(256, 1), th, 0, stream>>>(F, C5, lnrT, thetaT, o);
      hipMemsetAsync(g1, 0, 16384, stream);
      k_col_fft<1><<<dim3(128, 5), th, 0, stream>>>(C5);

      k_med_p1b<<<dim3(64, 1), th, 0, stream>>>(C5, 0, g1, 0);
      k_sel1b<<<dim3(1), th, 0, stream>>>(g1, sc1, g2, 0);
      k_med_p2b<<<dim3(64, 1), th, 0, stream>>>(C5, 0, sc1, g2, 0);
      k_sel2b<<<dim3(1), th, 0, stream>>>(g2, sc1, sc2, g3, 0);
      k_med_p3b<<<dim3(64, 1), th, 0, stream>>>(C5, 0, sc1, sc2, g3, 0);
      k_sel3b<<<dim3(1), th, 0, stream>>>(g3, sc1, sc2, Tval, 0);

      const double a = (double)o * (M_PI/6.0);
      k_pix<<<dim3(4096), th, 0, stream>>>(C5, Tval, (float)cos(a), (float)sin(a),
                                           ax2, ay2, axy, (o == 0) ? 1 : 0);
    }
    k_final<<<dim3(4096), th, 0, stream>>>(ax2, ay2, axy, out);
  }
}

// Round 16
// 391.351 us; speedup vs baseline: 1.3813x; 1.3813x over previous
//
#include <hip/hip_runtime.h>
#include <math.h>

typedef float2 c2;

#define S_IDX(i) ((i) ^ (((i) >> 5) & 15))
#define CSTR 1058                      // col-FFT H-exchange line stride in c2

__device__ __forceinline__ c2 cmul(c2 a, c2 b){
  return make_float2(a.x*b.x - a.y*b.y, a.x*b.y + a.y*b.x);
}

__constant__ float2 c_tw32[16] = {
  {1.0f, 0.0f},
  {0.980785280f, 0.195090322f},
  {0.923879533f, 0.382683432f},
  {0.831469612f, 0.555570233f},
  {0.707106781f, 0.707106781f},
  {0.555570233f, 0.831469612f},
  {0.382683432f, 0.923879533f},
  {0.195090322f, 0.980785280f},
  {0.0f, 1.0f},
  {-0.195090322f, 0.980785280f},
  {-0.382683432f, 0.923879533f},
  {-0.555570233f, 0.831469612f},
  {-0.707106781f, 0.707106781f},
  {-0.831469612f, 0.555570233f},
  {-0.923879533f, 0.382683432f},
  {-0.980785280f, 0.195090322f}
};

__constant__ float c_lnfo[5]  = {1.0986123f, 1.8405496f, 2.5824700f, 3.3244106f, 4.0663219f};
__constant__ float c_angl[6]  = {0.0f, 0.5235988f, 1.0471976f, 1.5707963f, 2.0943951f, 2.6179939f};
__constant__ float c_cosA[6] = {1.0f, 0.8660254038f, 0.5f, 6.123233996e-17f, -0.5f, -0.8660254038f};
__constant__ float c_sinA[6] = {0.0f, 0.5f, 0.8660254038f, 1.0f, 0.8660254038f, 0.5f};

// ---------------- Stockham row-FFT machinery (twiddle-precomputed) ----------------

template<int SIGN>
__device__ __forceinline__ void make_tw3(int t, c2* w1, c2* w2, c2* w3){
#pragma unroll
  for (int k = 0; k < 5; ++k){
    const int s = 1 << (2*k);
    const float ang = (float)SIGN * 0.00613592315154256f * (float)(t & ~(s-1));
    sincosf(ang, &w1[k].y, &w1[k].x);
    w2[k] = cmul(w1[k], w1[k]);
    w3[k] = cmul(w2[k], w1[k]);
  }
}

template<int SIGN>
__device__ __forceinline__ void fft1024(c2* bufA, c2* bufB, int t,
                                        const c2* w1a, const c2* w2a, const c2* w3a){
  c2* cur = bufA; c2* oth = bufB;
#pragma unroll
  for (int k = 0; k < 5; ++k){
    const int s = 1 << (2*k);
    const int q = t & (s - 1);
    c2 a = cur[S_IDX(t)];
    c2 b = cur[S_IDX(t + 256)];
    c2 c = cur[S_IDX(t + 512)];
    c2 d = cur[S_IDX(t + 768)];
    c2 apc = make_float2(a.x + c.x, a.y + c.y);
    c2 amc = make_float2(a.x - c.x, a.y - c.y);
    c2 bpd = make_float2(b.x + d.x, b.y + d.y);
    c2 bmd = make_float2(b.x - d.x, b.y - d.y);
    c2 y0 = make_float2(apc.x + bpd.x, apc.y + bpd.y);
    c2 e2 = make_float2(apc.x - bpd.x, apc.y - bpd.y);
    const float S4 = (float)SIGN;
    c2 u1 = make_float2(amc.x - S4*bmd.y, amc.y + S4*bmd.x);
    c2 u3 = make_float2(amc.x + S4*bmd.y, amc.y - S4*bmd.x);
    c2 y1 = cmul(u1, w1a[k]);
    c2 y2 = cmul(e2, w2a[k]);
    c2 y3 = cmul(u3, w3a[k]);
    const int bw = 4*t - 3*q;
    oth[S_IDX(bw)]       = y0;
    oth[S_IDX(bw + s)]   = y1;
    oth[S_IDX(bw + 2*s)] = y2;
    oth[S_IDX(bw + 3*s)] = y3;
    c2* tmp = cur; cur = oth; oth = tmp;
    __syncthreads();
  }
}

// ---------------- register FFT-32 + four-step column FFT (round-14 verified) ----------------

__device__ __forceinline__ constexpr int rev5(int k){
  return ((k&1)<<4) | ((k&2)<<2) | (k&4) | ((k&8)>>2) | ((k>>4)&1);
}

template<int SIGN, int M>
__device__ __forceinline__ void stage32(c2* r){
#pragma unroll
  for (int g = 0; g < 32; g += 2*M){
#pragma unroll
    for (int i = 0; i < M; ++i){
      const c2 a = r[g+i], b = r[g+i+M];
      r[g+i] = make_float2(a.x+b.x, a.y+b.y);
      c2 d = make_float2(a.x-b.x, a.y-b.y);
      if (i != 0){
        const float2 tt = c_tw32[i*(16/M)];
        d = cmul(d, make_float2(tt.x, (float)SIGN*tt.y));
      }
      r[g+i+M] = d;
    }
  }
}

template<int SIGN>
__device__ __forceinline__ void fft32(c2* r){
  stage32<SIGN,16>(r);
  stage32<SIGN,8>(r);
  stage32<SIGN,4>(r);
  stage32<SIGN,2>(r);
  stage32<SIGN,1>(r);
}

template<int SIGN>
__device__ __forceinline__ void fourstep_mid(c2* r, c2* line, int idx){
  const float ang = (float)SIGN * 0.006135923151542565f * (float)idx;
  c2 wst; sincosf(ang, &wst.y, &wst.x);
  c2 wc = make_float2(1.f, 0.f);
#pragma unroll
  for (int d = 0; d < 32; ++d){
    if ((d & 7) == 0 && d != 0){ float s, c; sincosf(ang*(float)d, &s, &c); wc = make_float2(c, s); }
    c2 v = r[rev5(d)];
    if (d != 0) v = cmul(v, wc);
    line[33*d + idx] = v;
    wc = cmul(wc, wst);
  }
  __syncthreads();
#pragma unroll
  for (int b = 0; b < 32; ++b) r[b] = line[33*idx + b];
  fft32<SIGN>(r);
}

// Column FFT: block owns 8 columns of one plane, in-place, direct global I/O.
template<int SIGN>
__global__ __launch_bounds__(256, 2) void k_col_fft(c2* __restrict__ Z){
  __shared__ c2 slab[8*CSTR];
  const int t = threadIdx.x;
  c2* base = Z + (size_t)blockIdx.y * 1048576;
  const int sub = t & 7, idx = t >> 3;
  const int col = blockIdx.x*8 + sub;
  c2 r[32];
#pragma unroll
  for (int a = 0; a < 32; ++a)
    r[a] = base[(size_t)(32*a + idx)*1024 + col];
  fft32<SIGN>(r);
  fourstep_mid<SIGN>(r, slab + sub*CSTR, idx);
#pragma unroll
  for (int c = 0; c < 32; ++c)
    base[(size_t)(32*c + idx)*1024 + col] = r[rev5(c)];
}

// ---------------- filter tables, [ky (row)][kx (col)] layout ----------------

__global__ __launch_bounds__(256) void k_filt_tab(float* __restrict__ lnrT, float* __restrict__ thetaT){
  const int r = blockIdx.x;           // ky
  const int t = threadIdx.x;
  const float yy = (float)(r < 512 ? r : r - 1024) * (1.0f/1024.0f);
#pragma unroll
  for (int j = 0; j < 4; ++j){
    const int c = t + 256*j;          // kx
    const float xx = (float)(c < 512 ? c : c - 1024) * (1.0f/1024.0f);
    const float radius = sqrtf(xx*xx + yy*yy);
    float lnr = logf(radius);
    if (r == 0 && c == 0) lnr = __int_as_float(0x7F800000);  // +inf -> filter 0 at DC
    lnrT[r*1024 + c] = lnr;
    thetaT[r*1024 + c] = atan2f(-yy, xx);
  }
}

// Row FFT of the real image: out[y][kx].
__global__ __launch_bounds__(256) void k_fft_fwd_real(const float* __restrict__ in, c2* __restrict__ out){
  const int t = threadIdx.x;
  __shared__ c2 bufA[1024];
  __shared__ c2 bufB[1024];
  c2 w1[5], w2[5], w3[5]; make_tw3<-1>(t, w1, w2, w3);
  for (int rr = 0; rr < 4; ++rr){
    const int row = blockIdx.x * 4 + rr;
    const float* src = in + (size_t)row * 1024;
    c2* dst = out + (size_t)row * 1024;
#pragma unroll
    for (int j = 0; j < 4; ++j){
      const int q = t + 256*j;
      bufA[S_IDX(q)] = make_float2(src[q], 0.0f);
    }
    __syncthreads();
    fft1024<-1>(bufA, bufB, t, w1, w2, w3);
#pragma unroll
    for (int j = 0; j < 4; ++j){ const int q = t + 256*j; dst[q] = bufB[S_IDX(q)]; }
    __syncthreads();
  }
}

// Orientation-grouped filter + row-IFFT over kx.  Row = ky of F[ky][kx].
__global__ __launch_bounds__(256) void k_fft_inv_filter_g(const c2* __restrict__ F, c2* __restrict__ Z,
                                                          const float* __restrict__ lnrT,
                                                          const float* __restrict__ thetaT, int orient0){
  const int t = threadIdx.x;
  const int orient = orient0 + blockIdx.y;
  const float angl = c_angl[orient];
  __shared__ c2 bufA[1024];
  __shared__ c2 bufB[1024];
  __shared__ c2 Frow[1024];
  __shared__ float commSh[1024];
  __shared__ float lnrSh[1024];
  c2 w1[5], w2[5], w3[5]; make_tw3<1>(t, w1, w2, w3);
  for (int rr = 0; rr < 4; ++rr){
    const int row = blockIdx.x * 4 + rr;      // ky
    const c2* src = F + (size_t)row * 1024;
    const float* lnrR = lnrT + (size_t)row * 1024;
    const float* thR  = thetaT + (size_t)row * 1024;
#pragma unroll
    for (int j = 0; j < 4; ++j){
      const int q = t + 256*j;
      Frow[q] = src[q];
      const float lnr = lnrR[q];
      const float th  = thR[q];
      const float lp = 1.0f/(1.0f + __expf(fmaf(30.f, lnr, 23.955231f)));
      float d = th - angl;
      if (d <= -3.14159274f) d += 6.28318548f;
      const float dth = fminf(fabsf(d)*3.0f, 3.14159274f);
      const float spr = 0.5f*(__cosf(dth)+1.0f);
      lnrSh[q] = lnr;
      commSh[q] = lp*spr;
    }
    __syncthreads();
    for (int s = 0; s < 5; ++s){
      const float lnfo = c_lnfo[s];
      c2* dst = Z + ((size_t)blockIdx.y*5 + s) * 1048576 + (size_t)row * 1024;
#pragma unroll
      for (int j = 0; j < 4; ++j){
        const int q = t + 256*j;
        const float u = lnrSh[q] + lnfo;
        const float f = __expf(-u*u*1.3989572f) * commSh[q];
        const c2 v = Frow[q];
        bufA[S_IDX(q)] = make_float2(v.x*f, v.y*f);
      }
      __syncthreads();
      fft1024<1>(bufA, bufB, t, w1, w2, w3);
#pragma unroll
      for (int j = 0; j < 4; ++j){ const int q = t + 256*j; dst[q] = bufB[S_IDX(q)]; }
      __syncthreads();
    }
  }
}

// ---------------- exact median via 3-level radix select (12/12/8 bits) ----------

__device__ __forceinline__ unsigned amp_bits(const c2 v){
  return __float_as_uint(sqrtf(v.x*v.x + v.y*v.y));
}

__global__ __launch_bounds__(256) void k_med_p1b(const c2* __restrict__ Zb, size_t oStride,
                                                 unsigned* __restrict__ g1, int oBase){
  __shared__ unsigned h[4][4096];
  const int t = threadIdx.x;
  const int wv = t >> 6;
  const c2* z0 = Zb + (size_t)blockIdx.y * oStride;
  unsigned* gg = g1 + (size_t)(oBase + blockIdx.y) * 4096;
  for (int j = t; j < 4*4096; j += 256) ((unsigned*)h)[j] = 0;
  __syncthreads();
  const int base = blockIdx.x * 16384;
  for (int it = 0; it < 64; ++it){
    const unsigned bits = amp_bits(z0[base + it*256 + t]);
    atomicAdd(&h[wv][bits >> 20], 1u);
  }
  __syncthreads();
  for (int j = t; j < 4096; j += 256){
    const unsigned s = h[0][j] + h[1][j] + h[2][j] + h[3][j];
    if (s) atomicAdd(&gg[j], s);
  }
}

__global__ __launch_bounds__(256) void k_sel1b(const unsigned* __restrict__ g1,
                                               unsigned* __restrict__ sc1,
                                               unsigned* __restrict__ g2, int oBase){
  __shared__ unsigned partial[256];
  const int t = threadIdx.x;
  const int oo = oBase + blockIdx.x;
  const unsigned* gg = g1 + (size_t)oo * 4096;
  unsigned loc[16]; unsigned s = 0;
#pragma unroll
  for (int j = 0; j < 16; ++j){ loc[j] = gg[t*16 + j]; s += loc[j]; }
  partial[t] = s;
  __syncthreads();
  unsigned p = 0;
  for (int u = 0; u < t; ++u) p += partial[u];
  for (int which = 0; which < 2; ++which){
    const unsigned R = 524287u + (unsigned)which;
    if (R >= p && R - p < s){
      unsigned cum = p;
      for (int j = 0; j < 16; ++j){
        if (R - cum < loc[j]){ sc1[oo*4 + which*2] = (unsigned)(t*16 + j); sc1[oo*4 + which*2+1] = R - cum; break; }
        cum += loc[j];
      }
    }
  }
  for (int j = t; j < 8192; j += 256) g2[(size_t)oo*8192 + j] = 0;
}

__global__ __launch_bounds__(256) void k_med_p2b(const c2* __restrict__ Zb, size_t oStride,
                                                 const unsigned* __restrict__ sc1,
                                                 unsigned* __restrict__ g2, int oBase){
  __shared__ unsigned h[2][4096];
  const int t = threadIdx.x;
  const int oo = oBase + blockIdx.y;
  const c2* z0 = Zb + (size_t)blockIdx.y * oStride;
  unsigned* gg = g2 + (size_t)oo * 8192;
  for (int j = t; j < 8192; j += 256) ((unsigned*)h)[j] = 0;
  __syncthreads();
  const unsigned b0 = sc1[oo*4 + 0], b1 = sc1[oo*4 + 2];
  const int base = blockIdx.x * 16384;
  for (int it = 0; it < 64; ++it){
    const unsigned bits = amp_bits(z0[base + it*256 + t]);
    const unsigned top = bits >> 20;
    const unsigned mid = (bits >> 8) & 4095u;
    if (top == b0)      atomicAdd(&h[0][mid], 1u);
    else if (top == b1) atomicAdd(&h[1][mid], 1u);
  }
  __syncthreads();
  for (int j = t; j < 4096; j += 256){
    if (h[0][j]) atomicAdd(&gg[j], h[0][j]);
    if (h[1][j]) atomicAdd(&gg[4096 + j], h[1][j]);
  }
}

__global__ __launch_bounds__(256) void k_sel2b(const unsigned* __restrict__ g2,
                                               const unsigned* __restrict__ sc1,
                                               unsigned* __restrict__ sc2,
                                               unsigned* __restrict__ g3, int oBase){
  __shared__ unsigned partial[256];
  const int t = threadIdx.x;
  const int oo = oBase + blockIdx.x;
  const unsigned b0 = sc1[oo*4+0], lr0 = sc1[oo*4+1], b1 = sc1[oo*4+2], lr1 = sc1[oo*4+3];
  for (int which = 0; which < 2; ++which){
    const unsigned* hh = g2 + (size_t)oo*8192 + ((which == 1 && b1 != b0) ? 4096 : 0);
    const unsigned R = which ? lr1 : lr0;
    unsigned loc[16]; unsigned s = 0;
#pragma unroll
    for (int j = 0; j < 16; ++j){ loc[j] = hh[t*16 + j]; s += loc[j]; }
    partial[t] = s;
    __syncthreads();
    unsigned p = 0;
    for (int u = 0; u < t; ++u) p += partial[u];
    if (R >= p && R - p < s){
      unsigned cum = p;
      for (int j = 0; j < 16; ++j){
        if (R - cum < loc[j]){ sc2[oo*4 + which*2] = (unsigned)(t*16 + j); sc2[oo*4 + which*2+1] = R - cum; break; }
        cum += loc[j];
      }
    }
    __syncthreads();
  }
  for (int j = t; j < 512; j += 256) g3[(size_t)oo*512 + j] = 0;
}

__global__ __launch_bounds__(256) void k_med_p3b(const c2* __restrict__ Zb, size_t oStride,
                                                 const unsigned* __restrict__ sc1,
                                                 const unsigned* __restrict__ sc2,
                                                 unsigned* __restrict__ g3, int oBase){
  __shared__ unsigned h[2][256];
  const int t = threadIdx.x;
  const int oo = oBase + blockIdx.y;
  const c2* z0 = Zb + (size_t)blockIdx.y * oStride;
  unsigned* gg = g3 + (size_t)oo * 512;
  h[0][t] = 0; h[1][t] = 0;
  __syncthreads();
  const unsigned k0 = (sc1[oo*4+0] << 12) | sc2[oo*4+0];
  const unsigned k1 = (sc1[oo*4+2] << 12) | sc2[oo*4+2];
  const int base = blockIdx.x * 16384;
  for (int it = 0; it < 64; ++it){
    const unsigned bits = amp_bits(z0[base + it*256 + t]);
    const unsigned key = bits >> 8;
    if (key == k0)       atomicAdd(&h[0][bits & 255u], 1u);
    else if (key == k1)  atomicAdd(&h[1][bits & 255u], 1u);
  }
  __syncthreads();
  if (h[0][t]) atomicAdd(&gg[t], h[0][t]);
  if (h[1][t]) atomicAdd(&gg[256 + t], h[1][t]);
}

__global__ __launch_bounds__(256) void k_sel3b(const unsigned* __restrict__ g3,
                                               const unsigned* __restrict__ sc1,
                                               const unsigned* __restrict__ sc2,
                                               float* __restrict__ Tval, int oBase){
  __shared__ unsigned partial[256];
  __shared__ float vres[2];
  const int t = threadIdx.x;
  const int oo = oBase + blockIdx.x;
  const unsigned k0 = (sc1[oo*4+0] << 12) | sc2[oo*4+0];
  const unsigned k1 = (sc1[oo*4+2] << 12) | sc2[oo*4+2];
  for (int which = 0; which < 2; ++which){
    const unsigned* hh = g3 + (size_t)oo*512 + ((which == 1 && k1 != k0) ? 256 : 0);
    const unsigned R = which ? sc2[oo*4+3] : sc2[oo*4+1];
    partial[t] = hh[t];
    __syncthreads();
    unsigned p = 0;
    for (int u = 0; u < t; ++u) p += partial[u];
    if (R >= p && R - p < partial[t]){
      const unsigned key = which ? k1 : k0;
      vres[which] = __uint_as_float((key << 8) | (unsigned)t);
    }
    __syncthreads();
  }
  if (t == 0){
    const float med = 0.5f * (vres[0] + vres[1]);
    const float tau = med / 1.17741001f;              // sqrt(ln 4)
    const float totalTau = tau * 1.8623464f;          // (1-(1/2.1)^5)/(1-1/2.1)
    const float T = totalTau * 1.25331414f + 2.0f * totalTau * 0.65513638f;
    Tval[oo] = T;
  }
}

// ---------------- fused per-pixel: all 6 orientations + final M,m ----------------

__global__ __launch_bounds__(256) void k_pix_all(const c2* __restrict__ Z, const float* __restrict__ Tval,
                                                 float* __restrict__ out){
  const int i = blockIdx.x * 256 + threadIdx.x;
  float covx2 = 0.f, covy2 = 0.f, covxy = 0.f;
#pragma unroll
  for (int o = 0; o < 6; ++o){
    const float T = Tval[o];
    float E[5], O[5];
    float sumE = 0.f, sumO = 0.f, sumAn = 0.f, maxAn = 0.f;
#pragma unroll
    for (int s = 0; s < 5; ++s){
      const c2 z = Z[(size_t)(o*5 + s) * 1048576 + i];
      O[s] = z.x; E[s] = z.y;
      const float an = sqrtf(z.x*z.x + z.y*z.y);
      sumE += E[s]; sumO += O[s]; sumAn += an; maxAn = fmaxf(maxAn, an);
    }
    const float XE = sqrtf(sumE*sumE + sumO*sumO) + 1e-4f;
    const float ME = sumE / XE, MO = sumO / XE;
    float energy = 0.f;
#pragma unroll
    for (int s = 0; s < 5; ++s)
      energy += E[s]*ME + O[s]*MO - fabsf(E[s]*MO - O[s]*ME);
    energy = fmaxf(energy - T, 0.f);
    const float width = (sumAn / (maxAn + 1e-4f) - 1.0f) * 0.25f;
    const float weight = 1.0f / (1.0f + expf((0.5f - width) * 10.0f));
    const float PC = weight * energy / sumAn;
    const float cx = PC * c_cosA[o], cy = PC * c_sinA[o];
    covx2 += cx*cx; covy2 += cy*cy; covxy += cx*cy;
  }
  covx2 *= (1.0f/3.0f);
  covy2 *= (1.0f/3.0f);
  covxy *= (4.0f/6.0f);
  const float dnm = sqrtf(covxy*covxy + (covx2 - covy2)*(covx2 - covy2)) + 1e-4f;
  const float ss = covy2 + covx2;
  out[i] = (ss + dnm) / 2.0f;
  out[1048576 + i] = (ss - dnm) / 2.0f;
}

// ---------------- fallback per-orientation pixel kernels ----------------

__global__ __launch_bounds__(256) void k_pix(const c2* __restrict__ Z, const float* __restrict__ Tp,
                                             float cA, float sA,
                                             float* __restrict__ ax2, float* __restrict__ ay2,
                                             float* __restrict__ axy, int first){
  const int i = blockIdx.x * 256 + threadIdx.x;
  const float T = *Tp;
  float E[5], O[5];
  float sumE = 0.f, sumO = 0.f, sumAn = 0.f, maxAn = 0.f;
#pragma unroll
  for (int s = 0; s < 5; ++s){
    const c2 z = Z[(size_t)s * 1048576 + i];
    O[s] = z.x; E[s] = z.y;
    const float an = sqrtf(z.x*z.x + z.y*z.y);
    sumE += E[s]; sumO += O[s]; sumAn += an; maxAn = fmaxf(maxAn, an);
  }
  const float XE = sqrtf(sumE*sumE + sumO*sumO) + 1e-4f;
  const float ME = sumE / XE, MO = sumO / XE;
  float energy = 0.f;
#pragma unroll
  for (int s = 0; s < 5; ++s)
    energy += E[s]*ME + O[s]*MO - fabsf(E[s]*MO - O[s]*ME);
  energy = fmaxf(energy - T, 0.f);
  const float width = (sumAn / (maxAn + 1e-4f) - 1.0f) * 0.25f;
  const float weight = 1.0f / (1.0f + expf((0.5f - width) * 10.0f));
  const float PC = weight * energy / sumAn;
  const float cx = PC * cA, cy = PC * sA;
  if (first){ ax2[i] = cx*cx; ay2[i] = cy*cy; axy[i] = cx*cy; }
  else      { ax2[i] += cx*cx; ay2[i] += cy*cy; axy[i] += cx*cy; }
}

__global__ __launch_bounds__(256) void k_final(const float* __restrict__ ax2, const float* __restrict__ ay2,
                                               const float* __restrict__ axy, float* __restrict__ out){
  const int i = blockIdx.x * 256 + threadIdx.x;
  const float cx2 = ax2[i] / 3.0f;
  const float cy2 = ay2[i] / 3.0f;
  const float cxy = 4.0f * axy[i] / 6.0f;
  const float dnm = sqrtf(cxy*cxy + (cx2 - cy2)*(cx2 - cy2)) + 1e-4f;
  const float ss = cy2 + cx2;
  out[i] = (ss + dnm) / 2.0f;
  out[1048576 + i] = (ss - dnm) / 2.0f;
}

extern "C" void kernel_launch(void* const* d_in, const int* in_sizes, int n_in,
                              void* d_out, int out_size, void* d_ws, size_t ws_size,
                              hipStream_t stream){
  (void)in_sizes; (void)n_in; (void)out_size;
  const float* img = (const float*)d_in[0];
  float* out = (float*)d_out;
  char* w = (char*)d_ws;

  const dim3 th(256);

  if (ws_size >= (size_t)268435456){
    // -------- full-batch path, 256 MiB --------
    c2* F  = (c2*)(w);
    c2* Z  = (c2*)(w + 8388608);
    float* lnrT   = (float*)(w + 260046848);
    float* thetaT = (float*)(w + 264241152);
    unsigned* g1  = (unsigned*)(w);             // aliases F; F's last read is filter_g
    unsigned* g2  = (unsigned*)(w + 98304);
    unsigned* g3  = (unsigned*)(w + 294912);
    unsigned* sc1 = (unsigned*)(w + 307200);
    unsigned* sc2 = (unsigned*)(w + 307328);
    float* Tval   = (float*)(w + 307456);

    k_filt_tab<<<dim3(1024), th, 0, stream>>>(lnrT, thetaT);

    // forward 2D FFT: rowFFT -> F[y][kx]; colFFT over y -> F[ky][kx]
    k_fft_fwd_real<<<dim3(256), th, 0, stream>>>(img, F);
    k_col_fft<-1><<<dim3(128, 1), th, 0, stream>>>(F);

    // 30 channels: filter + row IFFT over kx -> Z[ky][x]; col IFFT over ky -> z[y][x]
    k_fft_inv_filter_g<<<dim3(256, 6), th, 0, stream>>>(F, Z, lnrT, thetaT, 0);
    hipMemsetAsync(g1, 0, 6*16384, stream);     // F no longer needed
    k_col_fft<1><<<dim3(128, 30), th, 0, stream>>>(Z);

    // medians for 6 orientations (scale-0 planes)
    const size_t oStride = (size_t)5 * 1048576;
    k_med_p1b<<<dim3(64, 6), th, 0, stream>>>(Z, oStride, g1, 0);
    k_sel1b<<<dim3(6), th, 0, stream>>>(g1, sc1, g2, 0);
    k_med_p2b<<<dim3(64, 6), th, 0, stream>>>(Z, oStride, sc1, g2, 0);
    k_sel2b<<<dim3(6), th, 0, stream>>>(g2, sc1, sc2, g3, 0);
    k_med_p3b<<<dim3(64, 6), th, 0, stream>>>(Z, oStride, sc1, sc2, g3, 0);
    k_sel3b<<<dim3(6), th, 0, stream>>>(g3, sc1, sc2, Tval, 0);

    // fused per-pixel PC + covariance + M,m
    k_pix_all<<<dim3(4096), th, 0, stream>>>(Z, Tval, out);
  } else {
    // -------- fallback: per-orientation (~72 MB) --------
    c2* F   = (c2*)(w);
    c2* C5  = (c2*)(w + 8388608);                 // 5 planes, 40 MB
    float* lnrT   = (float*)(w + 50331648);
    float* thetaT = (float*)(w + 54525952);
    float* ax2 = (float*)(w + 58720256);
    float* ay2 = ax2 + 1048576;
    float* axy = ay2 + 1048576;
    unsigned* g1  = (unsigned*)(w + 71303168);
    unsigned* g2  = (unsigned*)(w + 71319552);
    unsigned* g3  = (unsigned*)(w + 71352320);
    unsigned* sc1 = (unsigned*)(w + 71354368);
    unsigned* sc2 = (unsigned*)(w + 71354496);
    float* Tval   = (float*)(w + 71354624);

    k_filt_tab<<<dim3(1024), th, 0, stream>>>(lnrT, thetaT);
    k_fft_fwd_real<<<dim3(256), th, 0, stream>>>(img, F);
    k_col_fft<-1><<<dim3(128, 1), th, 0, stream>>>(F);

    for (int o = 0; o < 6; ++o){
      k_fft_inv_filter_g<<<dim3(256, 1), th, 0, stream>>>(F, C5, lnrT, thetaT, o);
      hipMemsetAsync(g1, 0, 16384, stream);
      k_col_fft<1><<<dim3(128, 5), th, 0, stream>>>(C5);

      k_med_p1b<<<dim3(64, 1), th, 0, stream>>>(C5, 0, g1, 0);
      k_sel1b<<<dim3(1), th, 0, stream>>>(g1, sc1, g2, 0);
      k_med_p2b<<<dim3(64, 1), th, 0, stream>>>(C5, 0, sc1, g2, 0);
      k_sel2b<<<dim3(1), th, 0, stream>>>(g2, sc1, sc2, g3, 0);
      k_med_p3b<<<dim3(64, 1), th, 0, stream>>>(C5, 0, sc1, sc2, g3, 0);
      k_sel3b<<<dim3(1), th, 0, stream>>>(g3, sc1, sc2, Tval, 0);

      const double a = (double)o * (M_PI/6.0);
      k_pix<<<dim3(4096), th, 0, stream>>>(C5, Tval, (float)cos(a), (float)sin(a),
                                           ax2, ay2, axy, (o == 0) ? 1 : 0);
    }
    k_final<<<dim3(4096), th, 0, stream>>>(ax2, ay2, axy, out);
  }
}